// Round 3
// baseline (244.924 us; speedup 1.0000x reference)
//
#include <hip/hip_runtime.h>

#define NB 8
#define NA 9
#define HH 128
#define WW 128
#define NCELL (HH * WW)      // 16384
#define NTOT (NCELL * NA)    // 147456
#define PRE_K 2000
#define POST_K 300
#define CAP 4096
#define NMS_TH 0.7f

// anchor widths/heights (exact integers); all anchor centers are 16*(w,h)+8
__constant__ float c_aw[NA] = {184.f, 368.f, 736.f, 128.f, 256.f, 512.f, 88.f, 176.f, 352.f};
__constant__ float c_ah[NA] = {96.f, 192.f, 384.f, 128.f, 256.f, 512.f, 176.f, 352.f, 704.f};

__device__ __forceinline__ unsigned int sortable(float s) {
    unsigned int u = __float_as_uint(s);
    return (u & 0x80000000u) ? ~u : (u | 0x80000000u);
}

// ---------- 16-bit histogram, whole chip ----------
// grid (72, B) x 256; each block covers 2048 contiguous elems
__global__ void hist16_kernel(const float* __restrict__ scores,
                              unsigned int* __restrict__ hist) {
    int b = blockIdx.y;
    const float4* sp4 = (const float4*)(scores + (size_t)b * 18 * NCELL + (size_t)NA * NCELL);
    unsigned int* hb = hist + (size_t)b * 65536;
    int base4 = blockIdx.x * 512;  // 512 float4 per block
#pragma unroll
    for (int e = 0; e < 2; ++e) {
        float4 v = sp4[base4 + e * 256 + threadIdx.x];
        atomicAdd(&hb[sortable(v.x) >> 16], 1u);
        atomicAdd(&hb[sortable(v.y) >> 16], 1u);
        atomicAdd(&hb[sortable(v.z) >> 16], 1u);
        atomicAdd(&hb[sortable(v.w) >> 16], 1u);
    }
}

// ---------- pivot select over 64K bins, one block per batch ----------
__global__ __launch_bounds__(1024) void select16_kernel(const unsigned int* __restrict__ hist,
                                                        unsigned int* __restrict__ state) {
    __shared__ unsigned int thr[1024];
    int b = blockIdx.x;
    int tid = threadIdx.x;
    const uint4* hb4 = (const uint4*)(hist + (size_t)b * 65536);
    // each thread owns bins [tid*64, tid*64+64)
    uint4 q[16];
    unsigned int sum = 0;
#pragma unroll
    for (int k = 0; k < 16; ++k) {
        q[k] = hb4[tid * 16 + k];
        sum += q[k].x + q[k].y + q[k].z + q[k].w;
    }
    thr[tid] = sum;
    __syncthreads();
    // inclusive suffix scan: thr[t] = sum over t' >= t
    for (int off = 1; off < 1024; off <<= 1) {
        unsigned int v = (tid + off < 1024) ? thr[tid + off] : 0u;
        __syncthreads();
        thr[tid] += v;
        __syncthreads();
    }
    unsigned int above = (tid < 1023) ? thr[tid + 1] : 0u;  // count in bins > my segment
    if (thr[tid] >= (unsigned int)PRE_K && above < (unsigned int)PRE_K) {
        // pivot bin is inside my segment; walk from the top
        unsigned int acc = above;
        int pivot = tid * 64;
#pragma unroll
        for (int k = 63; k >= 0; --k) {
            unsigned int* qa = (unsigned int*)q;
            acc += qa[k];
            if (acc >= (unsigned int)PRE_K) { pivot = tid * 64 + k; break; }
        }
        state[b] = (unsigned int)pivot << 16;
    }
}

// ---------- gather candidates >= pivot, whole chip, 1 global atomic/block ----------
__global__ void gather_kernel(const float* __restrict__ scores,
                              const unsigned int* __restrict__ state,
                              int* __restrict__ cnt,
                              unsigned long long* __restrict__ buf) {
    __shared__ unsigned long long lbuf[2048];
    __shared__ int lcnt;
    __shared__ int gbase;
    int b = blockIdx.y;
    int tid = threadIdx.x;
    if (tid == 0) lcnt = 0;
    __syncthreads();
    unsigned int P = state[b];
    const float4* sp4 = (const float4*)(scores + (size_t)b * 18 * NCELL + (size_t)NA * NCELL);
    int base4 = blockIdx.x * 512;
#pragma unroll
    for (int e = 0; e < 2; ++e) {
        int t4 = base4 + e * 256 + tid;
        float4 v = sp4[t4];
        float el[4] = {v.x, v.y, v.z, v.w};
#pragma unroll
        for (int j = 0; j < 4; ++j) {
            unsigned int u = sortable(el[j]);
            if (u >= P) {
                int idx4 = t4 * 4 + j;            // = a*16384 + cell (channel-major)
                int a = idx4 >> 14;
                int cell = idx4 & 16383;
                unsigned int i = (unsigned int)cell * 9u + (unsigned int)a;
                int pos = atomicAdd(&lcnt, 1);
                lbuf[pos] = ((unsigned long long)u << 32) |
                            (unsigned long long)(0xFFFFFFFFu - i);
            }
        }
    }
    __syncthreads();
    if (tid == 0) gbase = atomicAdd(&cnt[b], lcnt);
    __syncthreads();
    int m = lcnt, gb = gbase;
    for (int t = tid; t < m; t += 256) {
        int g = gb + t;
        if (g < CAP) buf[(size_t)b * CAP + g] = lbuf[t];
    }
}

// ---------- per-batch bitonic sort (desc) + decode top-2000 ----------
__global__ __launch_bounds__(1024) void sortdecode_kernel(const unsigned long long* __restrict__ buf,
                                                          const int* __restrict__ cnt,
                                                          const float* __restrict__ deltas,
                                                          const float* __restrict__ im_info,
                                                          float4* __restrict__ props) {
    __shared__ unsigned long long s[CAP];
    int b = blockIdx.x;
    int tid = threadIdx.x;
    int n = min(cnt[b], CAP);
    int SZ = (n <= 2048) ? 2048 : CAP;
    for (int t = tid; t < SZ; t += 1024)
        s[t] = (t < n) ? buf[(size_t)b * CAP + t] : 0ULL;
    __syncthreads();
    for (int k = 2; k <= SZ; k <<= 1) {
        for (int j = k >> 1; j > 0; j >>= 1) {
            for (int t = tid; t < SZ; t += 1024) {
                int ixj = t ^ j;
                if (ixj > t) {
                    unsigned long long x = s[t], y = s[ixj];
                    if (((t & k) == 0) ? (x < y) : (x > y)) { s[t] = y; s[ixj] = x; }
                }
            }
            __syncthreads();
        }
    }
    // decode + clip (numerics identical to passing version)
    float maxx = __fsub_rn(im_info[b * 3 + 1], 1.0f);
    float maxy = __fsub_rn(im_info[b * 3 + 0], 1.0f);
    const float* dbase = deltas + (size_t)b * 36 * NCELL;
    for (int r = tid; r < PRE_K; r += 1024) {
        unsigned int i = 0xFFFFFFFFu - (unsigned int)(s[r] & 0xFFFFFFFFu);
        unsigned int cell = i / 9u;
        unsigned int a = i - cell * 9u;
        int wx = (int)(cell & 127u), hy = (int)(cell >> 7);
        const float* dp = dbase + (size_t)(4u * a) * NCELL + (size_t)hy * WW + wx;
        float dx = dp[0];
        float dy = dp[NCELL];
        float dw = dp[2 * NCELL];
        float dh = dp[3 * NCELL];
        float W_ = c_aw[a], H_ = c_ah[a];
        float cx = (float)(16 * wx + 8), cy = (float)(16 * hy + 8);
        float px = __fadd_rn(__fmul_rn(dx, W_), cx);
        float py = __fadd_rn(__fmul_rn(dy, H_), cy);
        float pw = __fmul_rn((float)exp((double)dw), W_);
        float ph = __fmul_rn((float)exp((double)dh), H_);
        float hw = __fmul_rn(0.5f, pw), hh = __fmul_rn(0.5f, ph);
        float x1 = __fsub_rn(px, hw), y1 = __fsub_rn(py, hh);
        float x2 = __fadd_rn(px, hw), y2 = __fadd_rn(py, hh);
        x1 = fminf(fmaxf(x1, 0.0f), maxx);
        y1 = fminf(fmaxf(y1, 0.0f), maxy);
        x2 = fminf(fmaxf(x2, 0.0f), maxx);
        y2 = fminf(fmaxf(y2, 0.0f), maxy);
        props[(size_t)b * PRE_K + r] = make_float4(x1, y1, x2, y2);
    }
}

// ---------------- NMS suppression bitmask ----------------
// grid (32 colBlocks, 32 rowBlocks, B), block 64
__global__ void mask_kernel(const float4* __restrict__ boxes,
                            unsigned long long* __restrict__ mask) {
    int colB = blockIdx.x, rowB = blockIdx.y, b = blockIdx.z;
    if (colB < rowB) return;
    __shared__ float4 cb[64];
    int t = threadIdx.x;
    int j0 = colB * 64;
    cb[t] = (j0 + t < PRE_K) ? boxes[(size_t)b * PRE_K + j0 + t] : make_float4(0.f, 0.f, -1.f, -1.f);
    __syncthreads();
    int i = rowB * 64 + t;
    if (i >= PRE_K) return;
    float4 mb = boxes[(size_t)b * PRE_K + i];
    float aarea = __fmul_rn(__fsub_rn(mb.z, mb.x), __fsub_rn(mb.w, mb.y));
    unsigned long long m = 0ULL;
    for (int jj = 0; jj < 64; ++jj) {
        int j = j0 + jj;
        if (j > i && j < PRE_K) {
            float4 c = cb[jj];
            float xx1 = fmaxf(mb.x, c.x), yy1 = fmaxf(mb.y, c.y);
            float xx2 = fminf(mb.z, c.z), yy2 = fminf(mb.w, c.w);
            float iw = fmaxf(__fsub_rn(xx2, xx1), 0.0f);
            float ih = fmaxf(__fsub_rn(yy2, yy1), 0.0f);
            float inter = __fmul_rn(iw, ih);
            float barea = __fmul_rn(__fsub_rn(c.z, c.x), __fsub_rn(c.w, c.y));
            float denom = __fadd_rn(__fsub_rn(__fadd_rn(aarea, barea), inter), 1e-9f);
            float iou = __fdiv_rn(inter, denom);
            if (iou > NMS_TH) m |= (1ULL << jj);
        }
    }
    mask[((size_t)(b * PRE_K + i)) * 32 + colB] = m;
}

// ---------------- serial greedy scan + output ----------------
#define CH 16
#define NCH (PRE_K / CH)  // 125

#define LOAD_CHUNK(BUF, C)                                               \
    _Pragma("unroll") for (int t = 0; t < CH; ++t) BUF[t] =              \
        act ? mrow[((size_t)((C) * CH + t)) * 32 + lane] : 0ULL;

#define PROCESS_CHUNK(BUF, CBASE)                                        \
    _Pragma("unroll") for (int t = 0; t < CH; ++t) {                     \
        int i = (CBASE) + t;                                             \
        int w = i >> 6;                                                  \
        unsigned long long rw = __shfl(remv, w, 64);                     \
        if (!((rw >> (i & 63)) & 1ULL)) {                                \
            if (lane == 0 && cnt < POST_K) keeplist[cnt] = i;            \
            cnt++;                                                       \
            if (lane >= w) remv |= BUF[t];                               \
        }                                                                \
    }

__global__ void scan_kernel(const unsigned long long* __restrict__ mask,
                            const float4* __restrict__ boxes,
                            float* __restrict__ out) {
    int b = blockIdx.x;
    int lane = threadIdx.x;
    const unsigned long long* mrow = mask + (size_t)b * PRE_K * 32;
    __shared__ int keeplist[POST_K];
    bool act = lane < 32;
    unsigned long long remv = 0ULL;
    int cnt = 0;
    unsigned long long bufA[CH], bufB[CH], bufC[CH];
    LOAD_CHUNK(bufA, 0)
    LOAD_CHUNK(bufB, 1)
    LOAD_CHUNK(bufC, 2)
    for (int c = 0; c < NCH; c += 3) {
        PROCESS_CHUNK(bufA, c * CH)
        if (cnt >= POST_K) break;
        if (c + 3 < NCH) { LOAD_CHUNK(bufA, c + 3) }
        if (c + 1 < NCH) {
            PROCESS_CHUNK(bufB, (c + 1) * CH)
            if (cnt >= POST_K) break;
            if (c + 4 < NCH) { LOAD_CHUNK(bufB, c + 4) }
        }
        if (c + 2 < NCH) {
            PROCESS_CHUNK(bufC, (c + 2) * CH)
            if (cnt >= POST_K) break;
            if (c + 5 < NCH) { LOAD_CHUNK(bufC, c + 5) }
        }
    }
    __syncthreads();
    int K = min(cnt, POST_K);
    const float4* bb = boxes + (size_t)b * PRE_K;
    for (int r = lane; r < POST_K; r += 64) {
        float4 v = make_float4(0.f, 0.f, 0.f, 0.f);
        if (r < K) v = bb[keeplist[r]];
        float* o = out + ((size_t)b * POST_K + r) * 5;
        o[0] = (float)b;
        o[1] = v.x;
        o[2] = v.y;
        o[3] = v.z;
        o[4] = v.w;
    }
}

// ---------------- launcher ----------------
extern "C" void kernel_launch(void* const* d_in, const int* in_sizes, int n_in,
                              void* d_out, int out_size, void* d_ws, size_t ws_size,
                              hipStream_t stream) {
    const float* scores = (const float*)d_in[0];
    const float* deltas = (const float*)d_in[1];
    const float* im_info = (const float*)d_in[2];
    float* out = (float*)d_out;
    char* ws = (char*)d_ws;

    // workspace layout (bytes)
    unsigned int* hist = (unsigned int*)(ws + 0);            // 8*65536*4 = 2097152
    int* cnt = (int*)(ws + 2097152);                         // 32
    unsigned int* state = (unsigned int*)(ws + 2097216);     // 32
    unsigned long long* buf = (unsigned long long*)(ws + 2097280); // 8*4096*8 = 262144
    float4* props = (float4*)(ws + 2359424);                 // 8*2000*16 = 256000
    unsigned long long* mask = (unsigned long long*)(ws + 2621440); // 8*2000*32*8 = 4096000
    // total ≈ 6.7 MB

    hipMemsetAsync(ws, 0, 2097152 + 64, stream);  // hist + cnt
    hipLaunchKernelGGL(hist16_kernel, dim3(72, NB), dim3(256), 0, stream, scores, hist);
    hipLaunchKernelGGL(select16_kernel, dim3(NB), dim3(1024), 0, stream, hist, state);
    hipLaunchKernelGGL(gather_kernel, dim3(72, NB), dim3(256), 0, stream, scores, state, cnt, buf);
    hipLaunchKernelGGL(sortdecode_kernel, dim3(NB), dim3(1024), 0, stream,
                       buf, cnt, deltas, im_info, props);
    hipLaunchKernelGGL(mask_kernel, dim3(32, 32, NB), dim3(64), 0, stream, props, mask);
    hipLaunchKernelGGL(scan_kernel, dim3(NB), dim3(64), 0, stream, mask, props, out);
}

// Round 4
// 120.590 us; speedup vs baseline: 2.0311x; 2.0311x over previous
//
#include <hip/hip_runtime.h>

#define NB 8
#define NA 9
#define HH 128
#define WW 128
#define NCELL (HH * WW)      // 16384
#define NTOT (NCELL * NA)    // 147456
#define PRE_K 2000
#define POST_K 300
#define CAP 4096
#define HBLK 18              // hist blocks per batch (1024 thr, 8192 elems each)
#define NMS_TH 0.7f

// anchor widths/heights (exact integers); all anchor centers are 16*(w,h)+8
__constant__ float c_aw[NA] = {184.f, 368.f, 736.f, 128.f, 256.f, 512.f, 88.f, 176.f, 352.f};
__constant__ float c_ah[NA] = {96.f, 192.f, 384.f, 128.f, 256.f, 512.f, 176.f, 352.f, 704.f};

__device__ __forceinline__ unsigned int sortable(float s) {
    unsigned int u = __float_as_uint(s);
    return (u & 0x80000000u) ? ~u : (u | 0x80000000u);
}

__device__ __forceinline__ unsigned long long shflx64(unsigned long long v, int m) {
    return __shfl_xor(v, m, 64);
}

// ---------- pass 0: 11-bit LDS histogram, per-block write-out (no atomic merge) ----------
// grid (HBLK, NB) x 1024; block covers 2048 float4 = 8192 elems
__global__ __launch_bounds__(1024) void hist0_kernel(const float* __restrict__ scores,
                                                     unsigned int* __restrict__ h0out) {
    __shared__ unsigned int h[2048];
    int b = blockIdx.y, tid = threadIdx.x;
    h[tid] = 0; h[tid + 1024] = 0;
    __syncthreads();
    const float4* sp4 = (const float4*)(scores + (size_t)b * 18 * NCELL + (size_t)NA * NCELL);
    int base4 = blockIdx.x * 2048;
#pragma unroll
    for (int e = 0; e < 2; ++e) {
        float4 v = sp4[base4 + e * 1024 + tid];
        atomicAdd(&h[sortable(v.x) >> 21], 1u);
        atomicAdd(&h[sortable(v.y) >> 21], 1u);
        atomicAdd(&h[sortable(v.z) >> 21], 1u);
        atomicAdd(&h[sortable(v.w) >> 21], 1u);
    }
    __syncthreads();
    unsigned int* o = h0out + ((size_t)(b * HBLK + blockIdx.x)) * 2048;
    o[tid] = h[tid];
    o[tid + 1024] = h[tid + 1024];
}

// ---------- select over 2048 bins (sum HBLK partials), one block per batch ----------
__global__ __launch_bounds__(1024) void select0_kernel(const unsigned int* __restrict__ h0out,
                                                       uint2* __restrict__ state0) {
    __shared__ unsigned int thr[1024];
    int b = blockIdx.x, tid = threadIdx.x;
    unsigned int c0 = 0, c1 = 0;
    for (int p = 0; p < HBLK; ++p) {
        const unsigned int* hp = h0out + ((size_t)(b * HBLK + p)) * 2048;
        uint2 v = *(const uint2*)&hp[2 * tid];
        c0 += v.x; c1 += v.y;
    }
    thr[tid] = c0 + c1;
    __syncthreads();
    for (int off = 1; off < 1024; off <<= 1) {
        unsigned int v = (tid + off < 1024) ? thr[tid + off] : 0u;
        __syncthreads();
        thr[tid] += v;
        __syncthreads();
    }
    unsigned int above = (tid < 1023) ? thr[tid + 1] : 0u;  // count(bins >= 2tid+2)
    if (thr[tid] >= (unsigned)PRE_K && above < (unsigned)PRE_K) {
        if (above + c1 >= (unsigned)PRE_K)
            state0[b] = make_uint2((unsigned)(2 * tid + 1), (unsigned)(PRE_K)-above);
        else
            state0[b] = make_uint2((unsigned)(2 * tid), (unsigned)(PRE_K)-above - c1);
    }
}

// ---------- pass 1: 7-bit refinement within pivot bin, 128-bin LDS hist ----------
__global__ __launch_bounds__(1024) void hist1_kernel(const float* __restrict__ scores,
                                                     const uint2* __restrict__ state0,
                                                     unsigned int* __restrict__ gh1) {
    __shared__ unsigned int h[128];
    int b = blockIdx.y, tid = threadIdx.x;
    if (tid < 128) h[tid] = 0;
    __syncthreads();
    unsigned int piv = state0[b].x;
    const float4* sp4 = (const float4*)(scores + (size_t)b * 18 * NCELL + (size_t)NA * NCELL);
    int base4 = blockIdx.x * 2048;
#pragma unroll
    for (int e = 0; e < 2; ++e) {
        float4 v = sp4[base4 + e * 1024 + tid];
        unsigned int u;
        u = sortable(v.x); if ((u >> 21) == piv) atomicAdd(&h[(u >> 14) & 127u], 1u);
        u = sortable(v.y); if ((u >> 21) == piv) atomicAdd(&h[(u >> 14) & 127u], 1u);
        u = sortable(v.z); if ((u >> 21) == piv) atomicAdd(&h[(u >> 14) & 127u], 1u);
        u = sortable(v.w); if ((u >> 21) == piv) atomicAdd(&h[(u >> 14) & 127u], 1u);
    }
    __syncthreads();
    if (tid < 128 && h[tid]) atomicAdd(&gh1[b * 128 + tid], h[tid]);
}

// ---------- select over 128 sub-bins, one wave per batch ----------
__global__ void select1_kernel(const unsigned int* __restrict__ gh1,
                               const uint2* __restrict__ state0,
                               unsigned int* __restrict__ state1) {
    int b = blockIdx.x, lane = threadIdx.x;  // 64 threads
    unsigned int c0 = 0, c1 = 0;
    if (lane < 64) {
        c0 = gh1[b * 128 + 2 * lane];
        c1 = gh1[b * 128 + 2 * lane + 1];
    }
    unsigned int sum = c0 + c1;
#pragma unroll
    for (int off = 1; off < 64; off <<= 1) {
        unsigned int v = __shfl_down(sum, off, 64);
        if (lane + off < 64) sum += v;
    }
    unsigned int above = __shfl_down(sum, 1, 64);
    if (lane == 63) above = 0;
    unsigned int need0 = state0[b].y;
    if (sum >= need0 && above < need0) {
        unsigned int d = (above + c1 >= need0) ? (unsigned)(2 * lane + 1) : (unsigned)(2 * lane);
        unsigned int prefix = (state0[b].x << 7) | d;   // 18-bit prefix
        state1[b] = prefix << 14;
    }
}

// ---------- gather candidates >= pivot, whole chip, 1 global atomic/block ----------
__global__ void gather_kernel(const float* __restrict__ scores,
                              const unsigned int* __restrict__ state1,
                              int* __restrict__ cnt,
                              unsigned long long* __restrict__ buf) {
    __shared__ unsigned long long lbuf[2048];
    __shared__ int lcnt;
    __shared__ int gbase;
    int b = blockIdx.y;
    int tid = threadIdx.x;
    if (tid == 0) lcnt = 0;
    __syncthreads();
    unsigned int P = state1[b];
    const float4* sp4 = (const float4*)(scores + (size_t)b * 18 * NCELL + (size_t)NA * NCELL);
    int base4 = blockIdx.x * 512;
#pragma unroll
    for (int e = 0; e < 2; ++e) {
        int t4 = base4 + e * 256 + tid;
        float4 v = sp4[t4];
        float el[4] = {v.x, v.y, v.z, v.w};
#pragma unroll
        for (int j = 0; j < 4; ++j) {
            unsigned int u = sortable(el[j]);
            if (u >= P) {
                int idx4 = t4 * 4 + j;            // = a*16384 + cell (channel-major)
                int a = idx4 >> 14;
                int cell = idx4 & 16383;
                unsigned int i = (unsigned int)cell * 9u + (unsigned int)a;
                int pos = atomicAdd(&lcnt, 1);
                lbuf[pos] = ((unsigned long long)u << 32) |
                            (unsigned long long)(0xFFFFFFFFu - i);
            }
        }
    }
    __syncthreads();
    if (tid == 0) gbase = atomicAdd(&cnt[b], lcnt);
    __syncthreads();
    int m = lcnt, gb = gbase;
    for (int t = tid; t < m; t += 256) {
        int g = gb + t;
        if (g < CAP) buf[(size_t)b * CAP + g] = lbuf[t];
    }
}

// ---------- per-batch sort: hybrid register-shuffle / LDS bitonic ----------
#define SHFL_STEP(J)                                                          \
    {                                                                         \
        int d_ = (J) >> 1;                                                    \
        bool keepMax = (((tid & d_) == 0) == (((2u * (unsigned)tid) & k) == 0)); \
        unsigned long long pa = shflx64(va, d_);                              \
        unsigned long long pb = shflx64(vb, d_);                              \
        va = keepMax ? (va > pa ? va : pa) : (va < pa ? va : pa);             \
        vb = keepMax ? (vb > pb ? vb : pb) : (vb < pb ? vb : pb);             \
    }
#define LOCAL_STEP()                                                          \
    {                                                                         \
        bool desc = (((2u * (unsigned)tid) & k) == 0);                        \
        unsigned long long lo = va < vb ? va : vb;                            \
        unsigned long long hi = va < vb ? vb : va;                            \
        va = desc ? hi : lo; vb = desc ? lo : hi;                             \
    }

__global__ __launch_bounds__(1024) void sort_kernel(const unsigned long long* __restrict__ buf,
                                                    const int* __restrict__ cnt,
                                                    unsigned int* __restrict__ topidx) {
    __shared__ unsigned long long s[CAP];
    int b = blockIdx.x;
    int tid = threadIdx.x;
    int n = min(cnt[b], CAP);
    const unsigned long long* src = buf + (size_t)b * CAP;
    if (n <= 2048) {
        // thread t owns elems 2t, 2t+1; shuffle stages for partner dist <= 32 lanes
        unsigned long long va = (2 * tid < n) ? src[2 * tid] : 0ULL;
        unsigned long long vb = (2 * tid + 1 < n) ? src[2 * tid + 1] : 0ULL;
#pragma unroll
        for (unsigned k = 2; k <= 128; k <<= 1) {
#pragma unroll
            for (unsigned j = k >> 1; j >= 2; j >>= 1) SHFL_STEP(j)
            LOCAL_STEP()
        }
        for (unsigned k = 256; k <= 2048; k <<= 1) {
            s[2 * tid] = va; s[2 * tid + 1] = vb;
            __syncthreads();
            for (unsigned j = k >> 1; j >= 128; j >>= 1) {
                for (int t = tid; t < 2048; t += 1024) {
                    int ixj = t ^ (int)j;
                    if (ixj > t) {
                        unsigned long long x = s[t], y = s[ixj];
                        if ((((unsigned)t & k) == 0) ? (x < y) : (x > y)) { s[t] = y; s[ixj] = x; }
                    }
                }
                __syncthreads();
            }
            va = s[2 * tid]; vb = s[2 * tid + 1];
#pragma unroll
            for (unsigned j = 64; j >= 2; j >>= 1) SHFL_STEP(j)
            LOCAL_STEP()
        }
        s[2 * tid] = va; s[2 * tid + 1] = vb;
        __syncthreads();
    } else {
        // rare fallback: plain LDS bitonic over 4096
        for (int t = tid; t < CAP; t += 1024)
            s[t] = (t < n) ? src[t] : 0ULL;
        __syncthreads();
        for (int k = 2; k <= CAP; k <<= 1) {
            for (int j = k >> 1; j > 0; j >>= 1) {
                for (int t = tid; t < CAP; t += 1024) {
                    int ixj = t ^ j;
                    if (ixj > t) {
                        unsigned long long x = s[t], y = s[ixj];
                        if (((t & k) == 0) ? (x < y) : (x > y)) { s[t] = y; s[ixj] = x; }
                    }
                }
                __syncthreads();
            }
        }
    }
    for (int r = tid; r < PRE_K; r += 1024)
        topidx[(size_t)b * PRE_K + r] = 0xFFFFFFFFu - (unsigned int)(s[r] & 0xFFFFFFFFu);
}

// ---------- decode + clip boxes, chip-wide ----------
__global__ void decode_kernel(const unsigned int* __restrict__ topidx,
                              const float* __restrict__ deltas,
                              const float* __restrict__ im_info,
                              float4* __restrict__ props) {
    int gid = blockIdx.x * 256 + threadIdx.x;
    if (gid >= NB * PRE_K) return;
    int b = gid / PRE_K;
    unsigned int i = topidx[gid];
    unsigned int cell = i / 9u;
    unsigned int a = i - cell * 9u;
    int wx = (int)(cell & 127u), hy = (int)(cell >> 7);
    const float* dp = deltas + (size_t)b * 36 * NCELL + (size_t)(4u * a) * NCELL +
                      (size_t)hy * WW + wx;
    float dx = dp[0];
    float dy = dp[NCELL];
    float dw = dp[2 * NCELL];
    float dh = dp[3 * NCELL];
    float W_ = c_aw[a], H_ = c_ah[a];
    float cx = (float)(16 * wx + 8), cy = (float)(16 * hy + 8);
    float px = __fadd_rn(__fmul_rn(dx, W_), cx);
    float py = __fadd_rn(__fmul_rn(dy, H_), cy);
    float pw = __fmul_rn((float)exp((double)dw), W_);
    float ph = __fmul_rn((float)exp((double)dh), H_);
    float hw = __fmul_rn(0.5f, pw), hh = __fmul_rn(0.5f, ph);
    float x1 = __fsub_rn(px, hw), y1 = __fsub_rn(py, hh);
    float x2 = __fadd_rn(px, hw), y2 = __fadd_rn(py, hh);
    float maxx = __fsub_rn(im_info[b * 3 + 1], 1.0f);
    float maxy = __fsub_rn(im_info[b * 3 + 0], 1.0f);
    x1 = fminf(fmaxf(x1, 0.0f), maxx);
    y1 = fminf(fmaxf(y1, 0.0f), maxy);
    x2 = fminf(fmaxf(x2, 0.0f), maxx);
    y2 = fminf(fmaxf(y2, 0.0f), maxy);
    props[gid] = make_float4(x1, y1, x2, y2);
}

// ---------------- NMS suppression bitmask ----------------
// grid (32 colBlocks, 32 rowBlocks, B), block 64
__global__ void mask_kernel(const float4* __restrict__ boxes,
                            unsigned long long* __restrict__ mask) {
    int colB = blockIdx.x, rowB = blockIdx.y, b = blockIdx.z;
    if (colB < rowB) return;
    __shared__ float4 cb[64];
    int t = threadIdx.x;
    int j0 = colB * 64;
    cb[t] = (j0 + t < PRE_K) ? boxes[(size_t)b * PRE_K + j0 + t] : make_float4(0.f, 0.f, -1.f, -1.f);
    __syncthreads();
    int i = rowB * 64 + t;
    if (i >= PRE_K) return;
    float4 mb = boxes[(size_t)b * PRE_K + i];
    float aarea = __fmul_rn(__fsub_rn(mb.z, mb.x), __fsub_rn(mb.w, mb.y));
    unsigned long long m = 0ULL;
    for (int jj = 0; jj < 64; ++jj) {
        int j = j0 + jj;
        if (j > i && j < PRE_K) {
            float4 c = cb[jj];
            float xx1 = fmaxf(mb.x, c.x), yy1 = fmaxf(mb.y, c.y);
            float xx2 = fminf(mb.z, c.z), yy2 = fminf(mb.w, c.w);
            float iw = fmaxf(__fsub_rn(xx2, xx1), 0.0f);
            float ih = fmaxf(__fsub_rn(yy2, yy1), 0.0f);
            float inter = __fmul_rn(iw, ih);
            float barea = __fmul_rn(__fsub_rn(c.z, c.x), __fsub_rn(c.w, c.y));
            float denom = __fadd_rn(__fsub_rn(__fadd_rn(aarea, barea), inter), 1e-9f);
            float iou = __fdiv_rn(inter, denom);
            if (iou > NMS_TH) m |= (1ULL << jj);
        }
    }
    mask[((size_t)(b * PRE_K + i)) * 32 + colB] = m;
}

// ---------------- serial greedy scan + output ----------------
// one shfl per 16-box word-aligned sub-chunk + one shfl per KEPT box only
#define CH 16
#define NCH (PRE_K / CH)  // 125

#define LOAD_CHUNK(BUF, C)                                               \
    _Pragma("unroll") for (int t = 0; t < CH; ++t) BUF[t] =              \
        act ? mrow[((size_t)((C) * CH + t)) * 32 + lane] : 0ULL;

#define PROCESS_CHUNK(BUF, CBASE)                                        \
    {                                                                    \
        int w = (CBASE) >> 6;                                            \
        unsigned long long rw = __shfl(remv, w, 64);                     \
        _Pragma("unroll") for (int t = 0; t < CH; ++t) {                 \
            int i = (CBASE) + t;                                         \
            if (!((rw >> (i & 63)) & 1ULL)) {                            \
                if (lane == 0 && cnt < POST_K) keeplist[cnt] = i;        \
                cnt++;                                                   \
                if (lane >= w) remv |= BUF[t];                           \
                rw |= __shfl(BUF[t], w, 64);                             \
            }                                                            \
        }                                                                \
    }

__global__ void scan_kernel(const unsigned long long* __restrict__ mask,
                            const float4* __restrict__ boxes,
                            float* __restrict__ out) {
    int b = blockIdx.x;
    int lane = threadIdx.x;
    const unsigned long long* mrow = mask + (size_t)b * PRE_K * 32;
    __shared__ int keeplist[POST_K];
    bool act = lane < 32;
    unsigned long long remv = 0ULL;
    int cnt = 0;
    unsigned long long bufA[CH], bufB[CH], bufC[CH];
    LOAD_CHUNK(bufA, 0)
    LOAD_CHUNK(bufB, 1)
    LOAD_CHUNK(bufC, 2)
    for (int c = 0; c < NCH; c += 3) {
        PROCESS_CHUNK(bufA, c * CH)
        if (cnt >= POST_K) break;
        if (c + 3 < NCH) { LOAD_CHUNK(bufA, c + 3) }
        if (c + 1 < NCH) {
            PROCESS_CHUNK(bufB, (c + 1) * CH)
            if (cnt >= POST_K) break;
            if (c + 4 < NCH) { LOAD_CHUNK(bufB, c + 4) }
        }
        if (c + 2 < NCH) {
            PROCESS_CHUNK(bufC, (c + 2) * CH)
            if (cnt >= POST_K) break;
            if (c + 5 < NCH) { LOAD_CHUNK(bufC, c + 5) }
        }
    }
    __syncthreads();
    int K = min(cnt, POST_K);
    const float4* bb = boxes + (size_t)b * PRE_K;
    for (int r = lane; r < POST_K; r += 64) {
        float4 v = make_float4(0.f, 0.f, 0.f, 0.f);
        if (r < K) v = bb[keeplist[r]];
        float* o = out + ((size_t)b * POST_K + r) * 5;
        o[0] = (float)b;
        o[1] = v.x;
        o[2] = v.y;
        o[3] = v.z;
        o[4] = v.w;
    }
}

// ---------------- launcher ----------------
extern "C" void kernel_launch(void* const* d_in, const int* in_sizes, int n_in,
                              void* d_out, int out_size, void* d_ws, size_t ws_size,
                              hipStream_t stream) {
    const float* scores = (const float*)d_in[0];
    const float* deltas = (const float*)d_in[1];
    const float* im_info = (const float*)d_in[2];
    float* out = (float*)d_out;
    char* ws = (char*)d_ws;

    // workspace layout (bytes)
    unsigned int* h0out = (unsigned int*)(ws + 0);                 // 18*8*2048*4 = 1179648
    unsigned int* gh1 = (unsigned int*)(ws + 1179648);             // 8*128*4 = 4096
    uint2* state0 = (uint2*)(ws + 1183744);                        // 64
    unsigned int* state1 = (unsigned int*)(ws + 1183808);          // 64
    int* cnt = (int*)(ws + 1183872);                               // 64
    unsigned long long* buf = (unsigned long long*)(ws + 1183936); // 8*4096*8 = 262144
    unsigned int* topidx = (unsigned int*)(ws + 1446080);          // 64000
    float4* props = (float4*)(ws + 1510080);                       // 256000
    unsigned long long* mask = (unsigned long long*)(ws + 1766080);// 4096000
    // total ≈ 5.86 MB

    hipMemsetAsync(ws + 1179648, 0, 4288, stream);  // gh1 + states + cnt
    hipLaunchKernelGGL(hist0_kernel, dim3(HBLK, NB), dim3(1024), 0, stream, scores, h0out);
    hipLaunchKernelGGL(select0_kernel, dim3(NB), dim3(1024), 0, stream, h0out, state0);
    hipLaunchKernelGGL(hist1_kernel, dim3(HBLK, NB), dim3(1024), 0, stream, scores, state0, gh1);
    hipLaunchKernelGGL(select1_kernel, dim3(NB), dim3(64), 0, stream, gh1, state0, state1);
    hipLaunchKernelGGL(gather_kernel, dim3(72, NB), dim3(256), 0, stream, scores, state1, cnt, buf);
    hipLaunchKernelGGL(sort_kernel, dim3(NB), dim3(1024), 0, stream, buf, cnt, topidx);
    hipLaunchKernelGGL(decode_kernel, dim3((NB * PRE_K + 255) / 256), dim3(256), 0, stream,
                       topidx, deltas, im_info, props);
    hipLaunchKernelGGL(mask_kernel, dim3(32, 32, NB), dim3(64), 0, stream, props, mask);
    hipLaunchKernelGGL(scan_kernel, dim3(NB), dim3(64), 0, stream, mask, props, out);
}

// Round 5
// 106.059 us; speedup vs baseline: 2.3093x; 1.1370x over previous
//
#include <hip/hip_runtime.h>

#define NB 8
#define NA 9
#define HH 128
#define WW 128
#define NCELL (HH * WW)      // 16384
#define NTOT (NCELL * NA)    // 147456
#define PRE_K 2000
#define POST_K 300
#define CAP 4096
#define HBLK 9               // hist blocks per batch (1024 thr, 16384 elems each)
#define NMS_TH 0.7f

// anchor widths/heights (exact integers); all anchor centers are 16*(w,h)+8
__constant__ float c_aw[NA] = {184.f, 368.f, 736.f, 128.f, 256.f, 512.f, 88.f, 176.f, 352.f};
__constant__ float c_ah[NA] = {96.f, 192.f, 384.f, 128.f, 256.f, 512.f, 176.f, 352.f, 704.f};

__device__ __forceinline__ unsigned int sortable(float s) {
    unsigned int u = __float_as_uint(s);
    return (u & 0x80000000u) ? ~u : (u | 0x80000000u);
}

__device__ __forceinline__ unsigned long long shflx64(unsigned long long v, int m) {
    return __shfl_xor(v, m, 64);
}

// ---------- pass 0: 11-bit LDS histogram, per-block write-out (no atomic merge) ----------
// grid (HBLK, NB) x 1024; block covers 4096 float4 = 16384 elems
__global__ __launch_bounds__(1024) void hist0_kernel(const float* __restrict__ scores,
                                                     unsigned int* __restrict__ h0out) {
    __shared__ unsigned int h[2048];
    int b = blockIdx.y, tid = threadIdx.x;
    h[tid] = 0; h[tid + 1024] = 0;
    __syncthreads();
    const float4* sp4 = (const float4*)(scores + (size_t)b * 18 * NCELL + (size_t)NA * NCELL);
    int base4 = blockIdx.x * 4096;
#pragma unroll
    for (int e = 0; e < 4; ++e) {
        float4 v = sp4[base4 + e * 1024 + tid];
        atomicAdd(&h[sortable(v.x) >> 21], 1u);
        atomicAdd(&h[sortable(v.y) >> 21], 1u);
        atomicAdd(&h[sortable(v.z) >> 21], 1u);
        atomicAdd(&h[sortable(v.w) >> 21], 1u);
    }
    __syncthreads();
    unsigned int* o = h0out + ((size_t)(b * HBLK + blockIdx.x)) * 2048;
    o[tid] = h[tid];
    o[tid + 1024] = h[tid + 1024];
}

// ---------- select over 2048 bins (sum HBLK partials); also zeroes gh1 + cnt ----------
__global__ __launch_bounds__(1024) void select0_kernel(const unsigned int* __restrict__ h0out,
                                                       uint2* __restrict__ state0,
                                                       unsigned int* __restrict__ gh1,
                                                       int* __restrict__ cnt) {
    __shared__ unsigned int thr[1024];
    int b = blockIdx.x, tid = threadIdx.x;
    if (tid < 128) gh1[b * 128 + tid] = 0;   // init for hist1 (runs after this kernel)
    if (tid == 0) cnt[b] = 0;                // init for gather
    unsigned int c0 = 0, c1 = 0;
    for (int p = 0; p < HBLK; ++p) {
        const unsigned int* hp = h0out + ((size_t)(b * HBLK + p)) * 2048;
        uint2 v = *(const uint2*)&hp[2 * tid];
        c0 += v.x; c1 += v.y;
    }
    thr[tid] = c0 + c1;
    __syncthreads();
    for (int off = 1; off < 1024; off <<= 1) {
        unsigned int v = (tid + off < 1024) ? thr[tid + off] : 0u;
        __syncthreads();
        thr[tid] += v;
        __syncthreads();
    }
    unsigned int above = (tid < 1023) ? thr[tid + 1] : 0u;  // count(bins >= 2tid+2)
    if (thr[tid] >= (unsigned)PRE_K && above < (unsigned)PRE_K) {
        if (above + c1 >= (unsigned)PRE_K)
            state0[b] = make_uint2((unsigned)(2 * tid + 1), (unsigned)(PRE_K)-above);
        else
            state0[b] = make_uint2((unsigned)(2 * tid), (unsigned)(PRE_K)-above - c1);
    }
}

// ---------- pass 1: 7-bit refinement within pivot bin, 128-bin LDS hist ----------
__global__ __launch_bounds__(1024) void hist1_kernel(const float* __restrict__ scores,
                                                     const uint2* __restrict__ state0,
                                                     unsigned int* __restrict__ gh1) {
    __shared__ unsigned int h[128];
    int b = blockIdx.y, tid = threadIdx.x;
    if (tid < 128) h[tid] = 0;
    __syncthreads();
    unsigned int piv = state0[b].x;
    const float4* sp4 = (const float4*)(scores + (size_t)b * 18 * NCELL + (size_t)NA * NCELL);
    int base4 = blockIdx.x * 4096;
#pragma unroll
    for (int e = 0; e < 4; ++e) {
        float4 v = sp4[base4 + e * 1024 + tid];
        unsigned int u;
        u = sortable(v.x); if ((u >> 21) == piv) atomicAdd(&h[(u >> 14) & 127u], 1u);
        u = sortable(v.y); if ((u >> 21) == piv) atomicAdd(&h[(u >> 14) & 127u], 1u);
        u = sortable(v.z); if ((u >> 21) == piv) atomicAdd(&h[(u >> 14) & 127u], 1u);
        u = sortable(v.w); if ((u >> 21) == piv) atomicAdd(&h[(u >> 14) & 127u], 1u);
    }
    __syncthreads();
    if (tid < 128 && h[tid]) atomicAdd(&gh1[b * 128 + tid], h[tid]);
}

// ---------- select over 128 sub-bins, one wave per batch ----------
__global__ void select1_kernel(const unsigned int* __restrict__ gh1,
                               const uint2* __restrict__ state0,
                               unsigned int* __restrict__ state1) {
    int b = blockIdx.x, lane = threadIdx.x;  // 64 threads
    unsigned int c0 = 0, c1 = 0;
    if (lane < 64) {
        c0 = gh1[b * 128 + 2 * lane];
        c1 = gh1[b * 128 + 2 * lane + 1];
    }
    unsigned int sum = c0 + c1;
#pragma unroll
    for (int off = 1; off < 64; off <<= 1) {
        unsigned int v = __shfl_down(sum, off, 64);
        if (lane + off < 64) sum += v;
    }
    unsigned int above = __shfl_down(sum, 1, 64);
    if (lane == 63) above = 0;
    unsigned int need0 = state0[b].y;
    if (sum >= need0 && above < need0) {
        unsigned int d = (above + c1 >= need0) ? (unsigned)(2 * lane + 1) : (unsigned)(2 * lane);
        unsigned int prefix = (state0[b].x << 7) | d;   // 18-bit prefix
        state1[b] = prefix << 14;
    }
}

// ---------- gather candidates >= pivot, whole chip, 1 global atomic/block ----------
__global__ void gather_kernel(const float* __restrict__ scores,
                              const unsigned int* __restrict__ state1,
                              int* __restrict__ cnt,
                              unsigned long long* __restrict__ buf) {
    __shared__ unsigned long long lbuf[2048];
    __shared__ int lcnt;
    __shared__ int gbase;
    int b = blockIdx.y;
    int tid = threadIdx.x;
    if (tid == 0) lcnt = 0;
    __syncthreads();
    unsigned int P = state1[b];
    const float4* sp4 = (const float4*)(scores + (size_t)b * 18 * NCELL + (size_t)NA * NCELL);
    int base4 = blockIdx.x * 512;
#pragma unroll
    for (int e = 0; e < 2; ++e) {
        int t4 = base4 + e * 256 + tid;
        float4 v = sp4[t4];
        float el[4] = {v.x, v.y, v.z, v.w};
#pragma unroll
        for (int j = 0; j < 4; ++j) {
            unsigned int u = sortable(el[j]);
            if (u >= P) {
                int idx4 = t4 * 4 + j;            // = a*16384 + cell (channel-major)
                int a = idx4 >> 14;
                int cell = idx4 & 16383;
                unsigned int i = (unsigned int)cell * 9u + (unsigned int)a;
                int pos = atomicAdd(&lcnt, 1);
                lbuf[pos] = ((unsigned long long)u << 32) |
                            (unsigned long long)(0xFFFFFFFFu - i);
            }
        }
    }
    __syncthreads();
    if (tid == 0) gbase = atomicAdd(&cnt[b], lcnt);
    __syncthreads();
    int m = lcnt, gb = gbase;
    for (int t = tid; t < m; t += 256) {
        int g = gb + t;
        if (g < CAP) buf[(size_t)b * CAP + g] = lbuf[t];
    }
}

// ---------- per-batch sort: hybrid register-shuffle / LDS bitonic ----------
#define SHFL_STEP(J)                                                          \
    {                                                                         \
        int d_ = (J) >> 1;                                                    \
        bool keepMax = (((tid & d_) == 0) == (((2u * (unsigned)tid) & k) == 0)); \
        unsigned long long pa = shflx64(va, d_);                              \
        unsigned long long pb = shflx64(vb, d_);                              \
        va = keepMax ? (va > pa ? va : pa) : (va < pa ? va : pa);             \
        vb = keepMax ? (vb > pb ? vb : pb) : (vb < pb ? vb : pb);             \
    }
#define LOCAL_STEP()                                                          \
    {                                                                         \
        bool desc = (((2u * (unsigned)tid) & k) == 0);                        \
        unsigned long long lo = va < vb ? va : vb;                            \
        unsigned long long hi = va < vb ? vb : va;                            \
        va = desc ? hi : lo; vb = desc ? lo : hi;                             \
    }

__global__ __launch_bounds__(1024) void sort_kernel(const unsigned long long* __restrict__ buf,
                                                    const int* __restrict__ cnt,
                                                    unsigned int* __restrict__ topidx) {
    __shared__ unsigned long long s[CAP];
    int b = blockIdx.x;
    int tid = threadIdx.x;
    int n = min(cnt[b], CAP);
    const unsigned long long* src = buf + (size_t)b * CAP;
    if (n <= 2048) {
        unsigned long long va = (2 * tid < n) ? src[2 * tid] : 0ULL;
        unsigned long long vb = (2 * tid + 1 < n) ? src[2 * tid + 1] : 0ULL;
#pragma unroll
        for (unsigned k = 2; k <= 128; k <<= 1) {
#pragma unroll
            for (unsigned j = k >> 1; j >= 2; j >>= 1) SHFL_STEP(j)
            LOCAL_STEP()
        }
        for (unsigned k = 256; k <= 2048; k <<= 1) {
            s[2 * tid] = va; s[2 * tid + 1] = vb;
            __syncthreads();
            for (unsigned j = k >> 1; j >= 128; j >>= 1) {
                for (int t = tid; t < 2048; t += 1024) {
                    int ixj = t ^ (int)j;
                    if (ixj > t) {
                        unsigned long long x = s[t], y = s[ixj];
                        if ((((unsigned)t & k) == 0) ? (x < y) : (x > y)) { s[t] = y; s[ixj] = x; }
                    }
                }
                __syncthreads();
            }
            va = s[2 * tid]; vb = s[2 * tid + 1];
#pragma unroll
            for (unsigned j = 64; j >= 2; j >>= 1) SHFL_STEP(j)
            LOCAL_STEP()
        }
        s[2 * tid] = va; s[2 * tid + 1] = vb;
        __syncthreads();
    } else {
        for (int t = tid; t < CAP; t += 1024)
            s[t] = (t < n) ? src[t] : 0ULL;
        __syncthreads();
        for (int k = 2; k <= CAP; k <<= 1) {
            for (int j = k >> 1; j > 0; j >>= 1) {
                for (int t = tid; t < CAP; t += 1024) {
                    int ixj = t ^ j;
                    if (ixj > t) {
                        unsigned long long x = s[t], y = s[ixj];
                        if (((t & k) == 0) ? (x < y) : (x > y)) { s[t] = y; s[ixj] = x; }
                    }
                }
                __syncthreads();
            }
        }
    }
    for (int r = tid; r < PRE_K; r += 1024)
        topidx[(size_t)b * PRE_K + r] = 0xFFFFFFFFu - (unsigned int)(s[r] & 0xFFFFFFFFu);
}

// ---------- decode + clip boxes, chip-wide ----------
__global__ void decode_kernel(const unsigned int* __restrict__ topidx,
                              const float* __restrict__ deltas,
                              const float* __restrict__ im_info,
                              float4* __restrict__ props) {
    int gid = blockIdx.x * 256 + threadIdx.x;
    if (gid >= NB * PRE_K) return;
    int b = gid / PRE_K;
    unsigned int i = topidx[gid];
    unsigned int cell = i / 9u;
    unsigned int a = i - cell * 9u;
    int wx = (int)(cell & 127u), hy = (int)(cell >> 7);
    const float* dp = deltas + (size_t)b * 36 * NCELL + (size_t)(4u * a) * NCELL +
                      (size_t)hy * WW + wx;
    float dx = dp[0];
    float dy = dp[NCELL];
    float dw = dp[2 * NCELL];
    float dh = dp[3 * NCELL];
    float W_ = c_aw[a], H_ = c_ah[a];
    float cx = (float)(16 * wx + 8), cy = (float)(16 * hy + 8);
    float px = __fadd_rn(__fmul_rn(dx, W_), cx);
    float py = __fadd_rn(__fmul_rn(dy, H_), cy);
    float pw = __fmul_rn((float)exp((double)dw), W_);
    float ph = __fmul_rn((float)exp((double)dh), H_);
    float hw = __fmul_rn(0.5f, pw), hh = __fmul_rn(0.5f, ph);
    float x1 = __fsub_rn(px, hw), y1 = __fsub_rn(py, hh);
    float x2 = __fadd_rn(px, hw), y2 = __fadd_rn(py, hh);
    float maxx = __fsub_rn(im_info[b * 3 + 1], 1.0f);
    float maxy = __fsub_rn(im_info[b * 3 + 0], 1.0f);
    x1 = fminf(fmaxf(x1, 0.0f), maxx);
    y1 = fminf(fmaxf(y1, 0.0f), maxy);
    x2 = fminf(fmaxf(x2, 0.0f), maxx);
    y2 = fminf(fmaxf(y2, 0.0f), maxy);
    props[gid] = make_float4(x1, y1, x2, y2);
}

// ---------------- NMS suppression bitmask, COLUMN form, word-major ----------------
// colm[(b*32 + iT)*2048 + j] : bit ii set iff box i=iT*64+ii suppresses box j (i<j, iou>th)
// grid (32 iTiles, 32 jTiles, B), block 64
__global__ void mask_kernel(const float4* __restrict__ boxes,
                            unsigned long long* __restrict__ colm) {
    int iT = blockIdx.x, jT = blockIdx.y, b = blockIdx.z;
    if (iT > jT) return;
    __shared__ float4 ib[64];
    int t = threadIdx.x;
    int i0 = iT * 64;
    ib[t] = (i0 + t < PRE_K) ? boxes[(size_t)b * PRE_K + i0 + t] : make_float4(0.f, 0.f, -1.f, -1.f);
    __syncthreads();
    int j = jT * 64 + t;
    if (j >= PRE_K) return;
    float4 jb = boxes[(size_t)b * PRE_K + j];
    float barea = __fmul_rn(__fsub_rn(jb.z, jb.x), __fsub_rn(jb.w, jb.y));
    unsigned long long m = 0ULL;
    for (int ii = 0; ii < 64; ++ii) {
        int i = i0 + ii;
        if (i < j) {   // i < j < PRE_K
            float4 c = ib[ii];
            float aarea = __fmul_rn(__fsub_rn(c.z, c.x), __fsub_rn(c.w, c.y));
            float xx1 = fmaxf(c.x, jb.x), yy1 = fmaxf(c.y, jb.y);
            float xx2 = fminf(c.z, jb.z), yy2 = fminf(c.w, jb.w);
            float iw = fmaxf(__fsub_rn(xx2, xx1), 0.0f);
            float ih = fmaxf(__fsub_rn(yy2, yy1), 0.0f);
            float inter = __fmul_rn(iw, ih);
            float denom = __fadd_rn(__fsub_rn(__fadd_rn(aarea, barea), inter), 1e-9f);
            float iou = __fdiv_rn(inter, denom);
            if (iou > NMS_TH) m |= (1ULL << ii);
        }
    }
    colm[((size_t)b * 32 + iT) * 2048 + j] = m;
}

// ---------------- greedy scan via ballots, one wave per batch ----------------
__global__ void scan_kernel(const unsigned long long* __restrict__ colm,
                            const float4* __restrict__ boxes,
                            float* __restrict__ out) {
    int b = blockIdx.x;
    int lane = threadIdx.x;  // 64 threads = 1 wave
    __shared__ unsigned long long kw[32];
    __shared__ int keeplist[POST_K];
    const unsigned long long* cb = colm + (size_t)b * 32 * 2048;
    int total = 0;
    bool done = false;
    for (int k = 0; k < 32 && !done; ++k) {
        int j = k * 64 + lane;
        // dead_j = suppressed by any earlier KEPT box (coalesced loads, 4-way ILP)
        unsigned long long d = 0;
        int w = 0;
        for (; w + 4 <= k; w += 4) {
            unsigned long long a0 = cb[(size_t)(w + 0) * 2048 + j] & kw[w + 0];
            unsigned long long a1 = cb[(size_t)(w + 1) * 2048 + j] & kw[w + 1];
            unsigned long long a2 = cb[(size_t)(w + 2) * 2048 + j] & kw[w + 2];
            unsigned long long a3 = cb[(size_t)(w + 3) * 2048 + j] & kw[w + 3];
            d |= (a0 | a1) | (a2 | a3);
        }
        for (; w < k; ++w) d |= cb[(size_t)w * 2048 + j] & kw[w];
        unsigned long long diag = cb[(size_t)k * 2048 + j];
        bool alive_me = (d == 0ULL) && (j < PRE_K);
        unsigned long long alive = __ballot(alive_me);
        unsigned long long keptw = 0ULL;
        while (alive) {
            int i = __builtin_ctzll(alive);
            keptw |= (1ULL << i);
            if (lane == 0) keeplist[total] = k * 64 + i;
            total++;
            if (total >= POST_K) { done = true; break; }
            unsigned long long sup = __ballot(((diag >> i) & 1ULL) != 0ULL);
            alive &= ~sup;
            alive &= ~keptw;
        }
        if (lane == 0) kw[k] = keptw;
        __syncthreads();
    }
    __syncthreads();
    int K = min(total, POST_K);
    const float4* bb = boxes + (size_t)b * PRE_K;
    for (int r = lane; r < POST_K; r += 64) {
        float4 v = make_float4(0.f, 0.f, 0.f, 0.f);
        if (r < K) v = bb[keeplist[r]];
        float* o = out + ((size_t)b * POST_K + r) * 5;
        o[0] = (float)b;
        o[1] = v.x;
        o[2] = v.y;
        o[3] = v.z;
        o[4] = v.w;
    }
}

// ---------------- launcher ----------------
extern "C" void kernel_launch(void* const* d_in, const int* in_sizes, int n_in,
                              void* d_out, int out_size, void* d_ws, size_t ws_size,
                              hipStream_t stream) {
    const float* scores = (const float*)d_in[0];
    const float* deltas = (const float*)d_in[1];
    const float* im_info = (const float*)d_in[2];
    float* out = (float*)d_out;
    char* ws = (char*)d_ws;

    // workspace layout (bytes)
    unsigned int* h0out = (unsigned int*)(ws + 0);                 // 9*8*2048*4 = 589824
    unsigned int* gh1 = (unsigned int*)(ws + 589824);              // 8*128*4 = 4096
    uint2* state0 = (uint2*)(ws + 593920);                         // 64
    unsigned int* state1 = (unsigned int*)(ws + 593984);           // 64
    int* cnt = (int*)(ws + 594048);                                // 64
    unsigned long long* buf = (unsigned long long*)(ws + 594112);  // 8*4096*8 = 262144
    unsigned int* topidx = (unsigned int*)(ws + 856256);           // 64000
    float4* props = (float4*)(ws + 920256);                        // 256000
    unsigned long long* colm = (unsigned long long*)(ws + 1176320);// 8*32*2048*8 = 4194304
    // total ≈ 5.37 MB; no memset needed (select0 zeroes gh1+cnt; rest written before read)

    hipLaunchKernelGGL(hist0_kernel, dim3(HBLK, NB), dim3(1024), 0, stream, scores, h0out);
    hipLaunchKernelGGL(select0_kernel, dim3(NB), dim3(1024), 0, stream, h0out, state0, gh1, cnt);
    hipLaunchKernelGGL(hist1_kernel, dim3(HBLK, NB), dim3(1024), 0, stream, scores, state0, gh1);
    hipLaunchKernelGGL(select1_kernel, dim3(NB), dim3(64), 0, stream, gh1, state0, state1);
    hipLaunchKernelGGL(gather_kernel, dim3(72, NB), dim3(256), 0, stream, scores, state1, cnt, buf);
    hipLaunchKernelGGL(sort_kernel, dim3(NB), dim3(1024), 0, stream, buf, cnt, topidx);
    hipLaunchKernelGGL(decode_kernel, dim3((NB * PRE_K + 255) / 256), dim3(256), 0, stream,
                       topidx, deltas, im_info, props);
    hipLaunchKernelGGL(mask_kernel, dim3(32, 32, NB), dim3(64), 0, stream, props, colm);
    hipLaunchKernelGGL(scan_kernel, dim3(NB), dim3(64), 0, stream, colm, props, out);
}